// Round 8
// baseline (1105.172 us; speedup 1.0000x reference)
//
#include <hip/hip_runtime.h>
#include <math.h>

#define BATCH  4
#define SEQ    1024
#define DM     512
#define DI     2048
#define NH     8
#define DH     64
#define NL     6
#define NOUT   2

typedef unsigned short u16;
typedef short s16x8 __attribute__((ext_vector_type(8)));
typedef float f32x4 __attribute__((ext_vector_type(4)));
typedef unsigned short u16x4 __attribute__((ext_vector_type(4)));

#define MFMA16(a, b, c) __builtin_amdgcn_mfma_f32_16x16x32_bf16((a), (b), (c), 0, 0, 0)

static constexpr float SQRT_D = 22.627416997969522f;

// per-layer bf16 weight slot layout (u16 element offsets)
#define SLOT_WO   786432     // after Wqkvt [1536][512]
#define SLOT_W1   1048576    // after Wot   [512][512]
#define SLOT_W2   2097152    // after W1t   [2048][512]
#define SLOT_E    3145728    // after W2t   [512][2048]
#define SLOT_SZ   3211264    // total u16 per layer (6.125 MB)

__device__ __forceinline__ u16 f2b(float x) {           // f32 -> bf16 (RNE)
    union { float f; unsigned u; } v; v.f = x;
    unsigned r = v.u + 0x7fffu + ((v.u >> 16) & 1u);
    return (u16)(r >> 16);
}
__device__ __forceinline__ float b2f(u16 b) {
    union { unsigned u; float f; } v; v.u = ((unsigned)b) << 16; return v.f;
}

// async global->LDS, 16B/lane. LDS dest = wave-uniform base + lane*16B.
// Lane l's global src must be row (l>>2), col-bytes (l&3)*16 relative to base.
__device__ __forceinline__ void gll16(const u16* g, const u16* l) {
    __builtin_amdgcn_global_load_lds(
        (const __attribute__((address_space(1))) unsigned int*)g,
        (__attribute__((address_space(3))) unsigned int*)l, 16, 0, 0);
}

// ---------------------------------------------------------------------------
// Embedding: h = emb[x]*sqrt(D) + pos   (writes f32 h and bf16 hb)
// ---------------------------------------------------------------------------
__global__ __launch_bounds__(256) void k_embed(const int* __restrict__ x,
                                               const float* __restrict__ emb,
                                               const float* __restrict__ pos,
                                               float* __restrict__ h,
                                               u16* __restrict__ hb) {
    const int idx = blockIdx.x * 256 + threadIdx.x;   // float4 index
    const int d4  = idx & 127;
    const int bs  = idx >> 7;
    const int s   = bs & (SEQ - 1);
    const int tok = x[bs];
    const float4 e = ((const float4*)emb)[tok * 128 + d4];
    const float4 p = ((const float4*)pos)[s * 128 + d4];
    float4 r;
    r.x = e.x * SQRT_D + p.x;  r.y = e.y * SQRT_D + p.y;
    r.z = e.z * SQRT_D + p.z;  r.w = e.w * SQRT_D + p.w;
    ((float4*)h)[idx] = r;
    u16x4 rb = { f2b(r.x), f2b(r.y), f2b(r.z), f2b(r.w) };
    ((u16x4*)hb)[idx] = rb;
}

// ---------------------------------------------------------------------------
// Weight convert+transpose to bf16 (1 or 6 layers per dispatch).
// ---------------------------------------------------------------------------
__global__ __launch_bounds__(256) void k_conv(const float* __restrict__ Wq, const float* __restrict__ Wk,
                                              const float* __restrict__ Wv, const float* __restrict__ Wo,
                                              const float* __restrict__ W1, const float* __restrict__ W2,
                                              const float* __restrict__ E,
                                              u16* __restrict__ wbase, int layer0, int slot_stride) {
    const int ll = blockIdx.x / 3136;
    const int tb = blockIdx.x - ll * 3136;
    const int layer = layer0 + ll;
    u16* Wqkvt = wbase + (size_t)ll * slot_stride;
    u16* Wot   = Wqkvt + SLOT_WO;
    u16* W1t   = Wqkvt + SLOT_W1;
    u16* W2t   = Wqkvt + SLOT_W2;
    u16* Ebf   = Wqkvt + SLOT_E;

    if (tb >= 3072) {                                   // E convert (no transpose)
        const int rem = tb - 3072;                      // 0..63
        const int idx = rem * 1024 + threadIdx.x * 4;
        const float4 v = *(const float4*)(E + (size_t)layer * SEQ * DH + idx);
        u16x4 o = { f2b(v.x), f2b(v.y), f2b(v.z), f2b(v.w) };
        *(u16x4*)(Ebf + idx) = o;
        return;
    }
    __shared__ float T[32][33];
    const float* src; u16* dst; int Ksz, Nsz, tk, tn;
    if (tb < 768) {
        const int mat = tb >> 8, rem = tb & 255;
        src = (mat == 0 ? Wq : (mat == 1 ? Wk : Wv)) + (size_t)layer * DM * DM;
        dst = Wqkvt + (size_t)mat * DM * DM;
        Ksz = 512; Nsz = 512; tk = rem & 15; tn = rem >> 4;
    } else if (tb < 1024) {
        const int rem = tb - 768;
        src = Wo + (size_t)layer * DM * DM; dst = Wot;
        Ksz = 512; Nsz = 512; tk = rem & 15; tn = rem >> 4;
    } else if (tb < 2048) {
        const int rem = tb - 1024;
        src = W1 + (size_t)layer * DM * DI; dst = W1t;
        Ksz = 512; Nsz = 2048; tk = rem & 15; tn = rem >> 4;
    } else {
        const int rem = tb - 2048;
        src = W2 + (size_t)layer * DI * DM; dst = W2t;
        Ksz = 2048; Nsz = 512; tk = rem >> 4; tn = rem & 15;
    }
    {
        const int rr = threadIdx.x >> 3, c4 = (threadIdx.x & 7) << 2;
        const float4 v = *(const float4*)(src + (size_t)(tk * 32 + rr) * Nsz + tn * 32 + c4);
        T[rr][c4 + 0] = v.x; T[rr][c4 + 1] = v.y; T[rr][c4 + 2] = v.z; T[rr][c4 + 3] = v.w;
    }
    __syncthreads();
    {
        const int nl = threadIdx.x >> 3, k4 = (threadIdx.x & 7) << 2;
        u16x4 o = { f2b(T[k4 + 0][nl]), f2b(T[k4 + 1][nl]), f2b(T[k4 + 2][nl]), f2b(T[k4 + 3][nl]) };
        *(u16x4*)(dst + (size_t)(tn * 32 + nl) * Ksz + tk * 32 + k4) = o;
    }
}

// ---------------------------------------------------------------------------
// V transpose: vb [B][SEQ][DM] bf16 -> Vt [B][DM][SEQ] bf16. grid (16,32,4).
// ---------------------------------------------------------------------------
__global__ __launch_bounds__(256) void k_vt(const u16* __restrict__ vb,
                                            u16* __restrict__ Vt) {
    __shared__ float T[32][33];
    const int tn = blockIdx.x;       // col tile (DM/32 = 16)
    const int tk = blockIdx.y;       // row tile (SEQ/32 = 32)
    const int b  = blockIdx.z;
    const u16* src = vb + (size_t)b * SEQ * DM;
    u16* dst = Vt + (size_t)b * DM * SEQ;
    {
        const int rr = threadIdx.x >> 3, c4 = (threadIdx.x & 7) << 2;
        const u16x4 v = *(const u16x4*)(src + (size_t)(tk * 32 + rr) * DM + tn * 32 + c4);
        T[rr][c4 + 0] = b2f(v.x); T[rr][c4 + 1] = b2f(v.y);
        T[rr][c4 + 2] = b2f(v.z); T[rr][c4 + 3] = b2f(v.w);
    }
    __syncthreads();
    {
        const int nl = threadIdx.x >> 3, k4 = (threadIdx.x & 7) << 2;
        u16x4 o = { f2b(T[k4 + 0][nl]), f2b(T[k4 + 1][nl]),
                    f2b(T[k4 + 2][nl]), f2b(T[k4 + 3][nl]) };
        *(u16x4*)(dst + (size_t)(tn * 32 + nl) * SEQ + tk * 32 + k4) = o;
    }
}

// ---------------------------------------------------------------------------
// MFMA GEMM, 128x128 tile, BK=32, 4 waves, global_load_lds staging
// (unpadded LDS [128][32] u16; wave w stages rows w*16..+15 and +64).
// Optional split-K over blockIdx.z (z=0 adds bias->Cf0, z=1 ->Cf1).
// ---------------------------------------------------------------------------
template <int RELU, int WRITE_BF16>
__global__ __launch_bounds__(256) void k_mm(const u16* __restrict__ A,
                                            const u16* __restrict__ Bt,
                                            const float* __restrict__ bias,
                                            float* __restrict__ Cf0,
                                            float* __restrict__ Cf1,
                                            u16* __restrict__ Cb,
                                            int K, int Kslice, int ldc) {
    __shared__ u16 As[128 * 32];
    __shared__ u16 Bs[128 * 32];

    const int n0 = blockIdx.x << 7;
    const int m0 = blockIdx.y << 7;
    const int zz = blockIdx.z;
    const int t  = threadIdx.x;
    const int lane = t & 63, w = t >> 6;
    const int n16 = lane & 15, quad = lane >> 4;
    const int wr = (w & 1) << 6;
    const int wc = (w >> 1) << 6;
    const int w16 = w << 4;            // wave staging row base

    const f32x4 z = {0.f, 0.f, 0.f, 0.f};
    f32x4 acc[4][4];
#pragma unroll
    for (int i = 0; i < 4; ++i)
#pragma unroll
        for (int j = 0; j < 4; ++j) acc[i][j] = z;

    // per-lane global src: row = t>>2 (= w*16 + lane>>2), col = (lane&3)*8 elems
    const int sr = t >> 2, sk = (t & 3) << 3;
    const int koff = zz * Kslice;
    const u16* Ag = A  + (size_t)(m0 + sr) * K + koff + sk;
    const u16* Bg = Bt + (size_t)(n0 + sr) * K + koff + sk;
    u16* Asw = As + w16 * 32;          // wave-uniform LDS dests
    u16* Bsw = Bs + w16 * 32;

    for (int k0 = 0; k0 < Kslice; k0 += 32) {
        __syncthreads();
        gll16(Ag + k0,                    Asw);
        gll16(Ag + (size_t)64 * K + k0,   Asw + 64 * 32);
        gll16(Bg + k0,                    Bsw);
        gll16(Bg + (size_t)64 * K + k0,   Bsw + 64 * 32);
        __syncthreads();

        s16x8 af[4], bfr[4];
#pragma unroll
        for (int rb = 0; rb < 4; ++rb)
            af[rb] = *(const s16x8*)&As[(wr + rb * 16 + n16) * 32 + quad * 8];
#pragma unroll
        for (int cb = 0; cb < 4; ++cb)
            bfr[cb] = *(const s16x8*)&Bs[(wc + cb * 16 + n16) * 32 + quad * 8];
#pragma unroll
        for (int rb = 0; rb < 4; ++rb)
#pragma unroll
            for (int cb = 0; cb < 4; ++cb)
                acc[rb][cb] = MFMA16(af[rb], bfr[cb], acc[rb][cb]);
    }

    float* Cf = zz ? Cf1 : Cf0;
#pragma unroll
    for (int cb = 0; cb < 4; ++cb) {
        const int col = n0 + wc + cb * 16 + n16;
        const float bv = (zz == 0) ? bias[col] : 0.f;
#pragma unroll
        for (int rb = 0; rb < 4; ++rb) {
#pragma unroll
            for (int rr = 0; rr < 4; ++rr) {
                const int row = m0 + wr + rb * 16 + quad * 4 + rr;
                float v = acc[rb][cb][rr] + bv;
                if (RELU) v = fmaxf(v, 0.f);
                const size_t idx = (size_t)row * ldc + col;
                if (WRITE_BF16) Cb[idx] = f2b(v);
                else            Cf[idx] = v;
            }
        }
    }
}

// ---------------------------------------------------------------------------
// MFMA GEMM, 64x128 tile, BK=32, 4 waves, global_load_lds staging.
// bf16 out, QKV-segmented. grid (N/128, 4096/64).
// ---------------------------------------------------------------------------
__global__ __launch_bounds__(256) void k_mm64(const u16* __restrict__ A,
                                              const u16* __restrict__ Bt,
                                              const float* __restrict__ bias0,
                                              const float* __restrict__ bias1,
                                              const float* __restrict__ bias2,
                                              u16* __restrict__ Cb,
                                              int K, int ldc, int seg_shift, size_t seg_stride) {
    __shared__ u16 As[64 * 32];
    __shared__ u16 Bs[128 * 32];

    const int n0 = blockIdx.x << 7;
    const int m0 = blockIdx.y << 6;
    const int t  = threadIdx.x;
    const int lane = t & 63, w = t >> 6;
    const int n16 = lane & 15, quad = lane >> 4;
    const int wc = w << 5;
    const int w16 = w << 4;

    const f32x4 z = {0.f, 0.f, 0.f, 0.f};
    f32x4 acc[4][2];
#pragma unroll
    for (int i = 0; i < 4; ++i) { acc[i][0] = z; acc[i][1] = z; }

    const int sr = t >> 2, sk = (t & 3) << 3;
    const u16* Ag = A  + (size_t)(m0 + sr) * K + sk;
    const u16* Bg = Bt + (size_t)(n0 + sr) * K + sk;
    u16* Asw = As + w16 * 32;
    u16* Bsw = Bs + w16 * 32;

    for (int k0 = 0; k0 < K; k0 += 32) {
        __syncthreads();
        gll16(Ag + k0,                  Asw);
        gll16(Bg + k0,                  Bsw);
        gll16(Bg + (size_t)64 * K + k0, Bsw + 64 * 32);
        __syncthreads();

        s16x8 af[4], bfr[2];
#pragma unroll
        for (int rb = 0; rb < 4; ++rb)
            af[rb] = *(const s16x8*)&As[(rb * 16 + n16) * 32 + quad * 8];
#pragma unroll
        for (int cb = 0; cb < 2; ++cb)
            bfr[cb] = *(const s16x8*)&Bs[(wc + cb * 16 + n16) * 32 + quad * 8];
#pragma unroll
        for (int rb = 0; rb < 4; ++rb)
#pragma unroll
            for (int cb = 0; cb < 2; ++cb)
                acc[rb][cb] = MFMA16(af[rb], bfr[cb], acc[rb][cb]);
    }

    const int sel = n0 >> seg_shift;
    const int colbase = (n0 & ((1 << seg_shift) - 1)) + wc;
    const float* bias = (sel == 0) ? bias0 : (sel == 1 ? bias1 : bias2);
    const size_t cbase = (size_t)sel * seg_stride;
#pragma unroll
    for (int cb = 0; cb < 2; ++cb) {
        const int col = colbase + cb * 16 + n16;
        const float bv = bias[col];
#pragma unroll
        for (int rb = 0; rb < 4; ++rb)
#pragma unroll
            for (int rr = 0; rr < 4; ++rr) {
                const int row = m0 + rb * 16 + quad * 4 + rr;
                Cb[cbase + (size_t)row * ldc + col] = f2b(acc[rb][cb][rr] + bv);
            }
    }
}

// ---------------------------------------------------------------------------
// MFMA flash relative attention. grid (16,8,4), 256 thr = 4 waves.
// K/V^T staged via reg-double-buffer; E fragments read DIRECTLY from global
// (128 KB/layer, L1/L2-hot) -> no Es LDS -> 45 KB LDS -> 3 blocks/CU.
// Incremental QE ring: arena bf16 col-major, phys col = (logical+64*ct)%128.
// Srel[ir][ic] = (d<=i0-c0) ? QE[ir][63+d] : 0, d = ic-ir. No online max.
// ---------------------------------------------------------------------------
__global__ __launch_bounds__(256) void k_attn(const u16* __restrict__ Qg,
                                              const u16* __restrict__ Kg,
                                              const u16* __restrict__ Vt,
                                              const u16* __restrict__ Eg,
                                              u16* __restrict__ Og) {
    __shared__ u16 Ks[64 * 72];
    __shared__ u16 Vts[64 * 72];      // Vts[d][j] = V[c0+j][d]
    __shared__ u16 Ps[64 * 72];
    __shared__ u16 arena[128 * 72];   // QE bf16, col-major; rows wave-private

    const int i0 = blockIdx.x << 6;
    const int hd = blockIdx.y;
    const int b  = blockIdx.z;
    const int t  = threadIdx.x;
    const int lane = t & 63;
    const int n16 = lane & 15;
    const int quad = lane >> 4;
    const int rw = (t >> 6) << 4;
    const int ir_base = rw + (quad << 2);
    const int a_last = i0 >> 6;
    const int eb0 = 960 - i0;

    const size_t gb  = (size_t)b * SEQ * DM + hd * DH;
    const size_t vtb = ((size_t)b * DM + hd * DH) * SEQ;

    const int r = t >> 3;              // staging row 0..31
    const int o = (t & 7) << 3;        // staging elem offset 0..56

    // Q fragments: iteration-invariant
    const u16* qp = Qg + gb + (size_t)(i0 + rw + n16) * DM + quad * 8;
    const s16x8 qa0 = *(const s16x8*)qp;
    const s16x8 qa1 = *(const s16x8*)(qp + 32);

    // preload ct=0 K/V tiles into registers
    uint4 kr0 = *(const uint4*)(Kg + gb + (size_t)r * DM + o);
    uint4 kr1 = *(const uint4*)(Kg + gb + (size_t)(r + 32) * DM + o);
    uint4 vr0 = *(const uint4*)(Vt + vtb + (size_t)r * SEQ + o);
    uint4 vr1 = *(const uint4*)(Vt + vtb + (size_t)(r + 32) * SEQ + o);

    const f32x4 z = {0.f, 0.f, 0.f, 0.f};
    f32x4 Oa[4] = {z, z, z, z};
    float l_run[4] = {0.f, 0.f, 0.f, 0.f};

    for (int ct = 0; ct < 16; ++ct) {
        const int c0 = ct << 6;
        const bool active = (ct <= a_last);

        __syncthreads();   // prior-iter consumers done
        *(uint4*)&Ks[r * 72 + o]         = kr0;
        *(uint4*)&Ks[(r + 32) * 72 + o]  = kr1;
        *(uint4*)&Vts[r * 72 + o]        = vr0;
        *(uint4*)&Vts[(r + 32) * 72 + o] = vr1;
        // prefetch ct+1 K/V into registers (overlaps with compute below)
        if (ct < 15) {
            const int cn = c0 + 64;
            kr0 = *(const uint4*)(Kg + gb + (size_t)(cn + r) * DM + o);
            kr1 = *(const uint4*)(Kg + gb + (size_t)(cn + r + 32) * DM + o);
            vr0 = *(const uint4*)(Vt + vtb + (size_t)r * SEQ + cn + o);
            vr1 = *(const uint4*)(Vt + vtb + (size_t)(r + 32) * SEQ + cn + o);
        }
        __syncthreads();   // tiles visible

        // ---- S = Q K^T
        f32x4 S[4];
#pragma unroll
        for (int cb = 0; cb < 4; ++cb) {
            const s16x8 k0 = *(const s16x8*)&Ks[(cb * 16 + n16) * 72 + quad * 8];
            const s16x8 k1 = *(const s16x8*)&Ks[(cb * 16 + n16) * 72 + quad * 8 + 32];
            S[cb] = MFMA16(qa0, k0, z);
            S[cb] = MFMA16(qa1, k1, S[cb]);
        }

        if (active) {
            const int eb = eb0 + c0;
            if (ct == 0) {       // full QE: logical cols 0..127, phys == logical
#pragma unroll
                for (int ub = 0; ub < 8; ++ub) {
                    int er = eb + ub * 16 + n16; er = er > 1023 ? 1023 : er;
                    const u16* ep = Eg + (size_t)er * DH + quad * 8;
                    f32x4 qe = MFMA16(qa0, *(const s16x8*)ep, z);
                    qe = MFMA16(qa1, *(const s16x8*)(ep + 32), qe);
                    u16x4 pk = { f2b(qe[0]), f2b(qe[1]), f2b(qe[2]), f2b(qe[3]) };
                    *(u16x4*)&arena[(ub * 16 + n16) * 72 + ir_base] = pk;
                }
            } else {             // incremental: new half, logical cols 64..127
                const int pb = ((ct + 1) & 1) << 6;
#pragma unroll
                for (int ub = 0; ub < 4; ++ub) {
                    int er = eb + 64 + ub * 16 + n16; er = er > 1023 ? 1023 : er;
                    const u16* ep = Eg + (size_t)er * DH + quad * 8;
                    f32x4 qe = MFMA16(qa0, *(const s16x8*)ep, z);
                    qe = MFMA16(qa1, *(const s16x8*)(ep + 32), qe);
                    u16x4 pk = { f2b(qe[0]), f2b(qe[1]), f2b(qe[2]), f2b(qe[3]) };
                    *(u16x4*)&arena[(pb + ub * 16 + n16) * 72 + ir_base] = pk;
                }
            }
            const int dqc = i0 - c0;
            const int rot = ct << 6;
#pragma unroll
            for (int cb = 0; cb < 4; ++cb)
#pragma unroll
                for (int rr = 0; rr < 4; ++rr) {
                    const int ir = ir_base + rr;
                    const int d = cb * 16 + n16 - ir;
                    const float srel = (d <= dqc)
                        ? b2f(arena[((63 + d + rot) & 127) * 72 + ir]) : 0.f;
                    S[cb][rr] = (S[cb][rr] + srel) * 0.125f;
                }
        } else {
#pragma unroll
            for (int cb = 0; cb < 4; ++cb)
#pragma unroll
                for (int rr = 0; rr < 4; ++rr) S[cb][rr] *= 0.125f;
        }

        // ---- softmax (no max-shift; logits bounded)
        float p[4][4];
#pragma unroll
        for (int cb = 0; cb < 4; ++cb)
#pragma unroll
            for (int rr = 0; rr < 4; ++rr) p[cb][rr] = __expf(S[cb][rr]);
#pragma unroll
        for (int rr = 0; rr < 4; ++rr) {
            float rs = p[0][rr] + p[1][rr] + p[2][rr] + p[3][rr];
            rs += __shfl_xor(rs, 1, 64);
            rs += __shfl_xor(rs, 2, 64);
            rs += __shfl_xor(rs, 4, 64);
            rs += __shfl_xor(rs, 8, 64);
            l_run[rr] += rs;
        }

        // ---- P -> wave-private LDS (A-operand layout), then PV
#pragma unroll
        for (int cb = 0; cb < 4; ++cb)
#pragma unroll
            for (int rr = 0; rr < 4; ++rr)
                Ps[(ir_base + rr) * 72 + cb * 16 + n16] = f2b(p[cb][rr]);

        const s16x8 pa0 = *(const s16x8*)&Ps[(rw + n16) * 72 + quad * 8];
        const s16x8 pa1 = *(const s16x8*)&Ps[(rw + n16) * 72 + quad * 8 + 32];
#pragma unroll
        for (int db = 0; db < 4; ++db) {
            const s16x8 v0 = *(const s16x8*)&Vts[(db * 16 + n16) * 72 + quad * 8];
            const s16x8 v1 = *(const s16x8*)&Vts[(db * 16 + n16) * 72 + quad * 8 + 32];
            Oa[db] = MFMA16(pa0, v0, Oa[db]);
            Oa[db] = MFMA16(pa1, v1, Oa[db]);
        }
    }

#pragma unroll
    for (int rr = 0; rr < 4; ++rr) l_run[rr] = 1.f / l_run[rr];
#pragma unroll
    for (int db = 0; db < 4; ++db)
#pragma unroll
        for (int rr = 0; rr < 4; ++rr) {
            const int row = i0 + ir_base + rr;
            Og[gb + (size_t)row * DM + db * 16 + n16] = f2b(Oa[db][rr] * l_run[rr]);
        }
}

// ---------------------------------------------------------------------------
// LayerNorm(A + R)*sc + bi -> Y (f32, may alias A) and Yb. 2 rows/block.
// ---------------------------------------------------------------------------
__global__ __launch_bounds__(256) void k_ln(const float* __restrict__ A,
                                            const float* __restrict__ R,
                                            const float* __restrict__ sc,
                                            const float* __restrict__ bi,
                                            float* __restrict__ Y,
                                            u16* __restrict__ Yb) {
    const int g = threadIdx.x >> 7;
    const int r = (blockIdx.x << 1) + g;
    const int t = threadIdx.x & 127;
    const int w = threadIdx.x >> 6;
    const float4 a = ((const float4*)(A + (size_t)r * DM))[t];
    const float4 b = ((const float4*)(R + (size_t)r * DM))[t];
    float4 v;
    v.x = a.x + b.x; v.y = a.y + b.y; v.z = a.z + b.z; v.w = a.w + b.w;

    float s = v.x + v.y + v.z + v.w;
#pragma unroll
    for (int o = 32; o > 0; o >>= 1) s += __shfl_down(s, o, 64);
    __shared__ float r1[4], r2[4];
    if ((threadIdx.x & 63) == 0) r1[w] = s;
    __syncthreads();
    const float mean = (r1[g << 1] + r1[(g << 1) + 1]) * (1.f / 512.f);

    float4 d;
    d.x = v.x - mean; d.y = v.y - mean; d.z = v.z - mean; d.w = v.w - mean;
    float q = d.x * d.x + d.y * d.y + d.z * d.z + d.w * d.w;
#pragma unroll
    for (int o = 32; o > 0; o >>= 1) q += __shfl_down(q, o, 64);
    if ((threadIdx.x & 63) == 0) r2[w] = q;
    __syncthreads();
    const float rsq = rsqrtf((r2[g << 1] + r2[(g << 1) + 1]) * (1.f / 512.f) + 1e-6f);

    const float4 s4 = ((const float4*)sc)[t];
    const float4 b4 = ((const float4*)bi)[t];
    float4 y;
    y.x = d.x * rsq * s4.x + b4.x;
    y.y = d.y * rsq * s4.y + b4.y;
    y.z = d.z * rsq * s4.z + b4.z;
    y.w = d.w * rsq * s4.w + b4.w;
    ((float4*)(Y + (size_t)r * DM))[t] = y;
    u16x4 yb = { f2b(y.x), f2b(y.y), f2b(y.z), f2b(y.w) };
    ((u16x4*)(Yb + (size_t)r * DM))[t] = yb;
}

// ---------------------------------------------------------------------------
// LayerNorm(A0 + A1 + R)*sc + bi -> Y, Yb   (split-K partial sum fused in).
// ---------------------------------------------------------------------------
__global__ __launch_bounds__(256) void k_ln3(const float* __restrict__ A0,
                                             const float* __restrict__ A1,
                                             const float* __restrict__ R,
                                             const float* __restrict__ sc,
                                             const float* __restrict__ bi,
                                             float* __restrict__ Y,
                                             u16* __restrict__ Yb) {
    const int g = threadIdx.x >> 7;
    const int r = (blockIdx.x << 1) + g;
    const int t = threadIdx.x & 127;
    const int w = threadIdx.x >> 6;
    const float4 a0 = ((const float4*)(A0 + (size_t)r * DM))[t];
    const float4 a1 = ((const float4*)(A1 + (size_t)r * DM))[t];
    const float4 b  = ((const float4*)(R  + (size_t)r * DM))[t];
    float4 v;
    v.x = a0.x + a1.x + b.x; v.y = a0.y + a1.y + b.y;
    v.z = a0.z + a1.z + b.z; v.w = a0.w + a1.w + b.w;

    float s = v.x + v.y + v.z + v.w;
#pragma unroll
    for (int o = 32; o > 0; o >>= 1) s += __shfl_down(s, o, 64);
    __shared__ float r1[4], r2[4];
    if ((threadIdx.x & 63) == 0) r1[w] = s;
    __syncthreads();
    const float mean = (r1[g << 1] + r1[(g << 1) + 1]) * (1.f / 512.f);

    float4 d;
    d.x = v.x - mean; d.y = v.y - mean; d.z = v.z - mean; d.w = v.w - mean;
    float q = d.x * d.x + d.y * d.y + d.z * d.z + d.w * d.w;
#pragma unroll
    for (int o = 32; o > 0; o >>= 1) q += __shfl_down(q, o, 64);
    if ((threadIdx.x & 63) == 0) r2[w] = q;
    __syncthreads();
    const float rsq = rsqrtf((r2[g << 1] + r2[(g << 1) + 1]) * (1.f / 512.f) + 1e-6f);

    const float4 s4 = ((const float4*)sc)[t];
    const float4 b4 = ((const float4*)bi)[t];
    float4 y;
    y.x = d.x * rsq * s4.x + b4.x;
    y.y = d.y * rsq * s4.y + b4.y;
    y.z = d.z * rsq * s4.z + b4.z;
    y.w = d.w * rsq * s4.w + b4.w;
    ((float4*)(Y + (size_t)r * DM))[t] = y;
    u16x4 yb = { f2b(y.x), f2b(y.y), f2b(y.z), f2b(y.w) };
    ((u16x4*)(Yb + (size_t)r * DM))[t] = yb;
}

// ---------------------------------------------------------------------------
// out[b,o] = tanh(h[b,0,:] @ Wf[:,o] + bf[o])
// ---------------------------------------------------------------------------
__global__ __launch_bounds__(512) void k_head(const float* __restrict__ h,
                                              const float* __restrict__ Wf,
                                              const float* __restrict__ bf,
                                              float* __restrict__ out) {
    const int t = threadIdx.x;
    const int w = t >> 6, lane = t & 63;
    const int b = w >> 1, oo = w & 1;
    float s = 0.f;
    for (int d = lane; d < DM; d += 64)
        s += h[(size_t)b * SEQ * DM + d] * Wf[d * NOUT + oo];
#pragma unroll
    for (int o = 32; o > 0; o >>= 1) s += __shfl_down(s, o, 64);
    if (lane == 0) out[b * NOUT + oo] = tanhf(s + bf[oo]);
}

// ---------------------------------------------------------------------------
extern "C" void kernel_launch(void* const* d_in, const int* in_sizes, int n_in,
                              void* d_out, int out_size, void* d_ws, size_t ws_size,
                              hipStream_t stream) {
    const int*   x    = (const int*)d_in[0];
    const float* emb  = (const float*)d_in[1];
    const float* pos  = (const float*)d_in[2];
    const float* Wq   = (const float*)d_in[3];
    const float* bq   = (const float*)d_in[4];
    const float* Wk   = (const float*)d_in[5];
    const float* bk   = (const float*)d_in[6];
    const float* Wv   = (const float*)d_in[7];
    const float* bv   = (const float*)d_in[8];
    const float* Wo   = (const float*)d_in[9];
    const float* bo   = (const float*)d_in[10];
    const float* E    = (const float*)d_in[11];
    const float* W1   = (const float*)d_in[12];
    const float* b1   = (const float*)d_in[13];
    const float* W2   = (const float*)d_in[14];
    const float* b2   = (const float*)d_in[15];
    const float* ln1s = (const float*)d_in[16];
    const float* ln1b = (const float*)d_in[17];
    const float* ln2s = (const float*)d_in[18];
    const float* ln2b = (const float*)d_in[19];
    const float* Wf   = (const float*)d_in[20];
    const float* bfp  = (const float*)d_in[21];
    float* out = (float*)d_out;

    // Workspace map (no trailing backslash in these comments!)
    char* W = (char*)d_ws;
    float* h    = (float*)(W);                   // 8 MB f32 residual
    float* h1   = (float*)(W + (8u  << 20));     // 8 MB f32
    u16*   hb   = (u16*)  (W + (16u << 20));     // 4 MB bf16 of h
    u16*   h1b  = (u16*)  (W + (20u << 20));     // 4 MB bf16 of h1 (FFN phase)
    u16*   Vt   = h1b;                           // Vt [B][DM][SEQ] aliases h1b (attn phase)
    u16*   qb   = (u16*)  (W + (24u << 20));     // 4 MB q
    u16*   kb   = (u16*)  (W + (28u << 20));     // 4 MB k
    u16*   vb   = (u16*)  (W + (32u << 20));     // 4 MB v (row-major)
    u16*   tb   = (u16*)  (W + (36u << 20));     // 4 MB attention out
    u16*   midb = qb;                            // FFN inner [4096][2048], aliases 24..40 MB
    float* P1   = (float*)(W + (24u << 20));     // Wo split partial, aliases qb+kb (dead then)
    u16*   Wb   = (u16*)  (W + (40u << 20));     // weight slots (1 or 6 x 6.125 MB)

    // all-layer weight conversion if workspace allows (40 + 6*6.125 = 76.75 MB)
    const bool all = ws_size >= (size_t)80478208ull;
    // FFN2 split partial region right after the weight slots, if room
    const size_t off_p2 = (40ull << 20) + (size_t)(all ? 6 : 1) * SLOT_SZ * 2;
    const bool splitF2 = ws_size >= off_p2 + (8ull << 20);
    float* P2 = (float*)(W + off_p2);

    const int M = BATCH * SEQ;                   // 4096
    const size_t SEG = (size_t)M * DM;           // q->k->v segment stride (elems)

    k_embed<<<(BATCH * SEQ * DM / 4) / 256, 256, 0, stream>>>(x, emb, pos, h, hb);
    if (all)
        k_conv<<<6 * 3136, 256, 0, stream>>>(Wq, Wk, Wv, Wo, W1, W2, E, Wb, 0, SLOT_SZ);

    for (int l = 0; l < NL; ++l) {
        if (!all)
            k_conv<<<3136, 256, 0, stream>>>(Wq, Wk, Wv, Wo, W1, W2, E, Wb, l, 0);
        u16* wl   = Wb + (size_t)(all ? l : 0) * SLOT_SZ;
        u16* wqkv = wl;
        u16* wot  = wl + SLOT_WO;
        u16* w1t  = wl + SLOT_W1;
        u16* w2t  = wl + SLOT_W2;
        u16* ebf  = wl + SLOT_E;

        // QKV: 64x128 tiles, 768 blocks (3/CU)
        k_mm64<<<dim3(12, 64), 256, 0, stream>>>(hb, wqkv,
            bq + l * DM, bk + l * DM, bv + l * DM, qb, 512, 512, 9, SEG);
        k_vt<<<dim3(16, 32, 4), 256, 0, stream>>>(vb, Vt);
        k_attn<<<dim3(16, 8, 4), 256, 0, stream>>>(qb, kb, Vt, ebf, tb);
        // Wo: split-K=2 (256 blocks), partials summed inside k_ln3
        k_mm<0, 0><<<dim3(4, 32, 2), 256, 0, stream>>>(tb, wot,
            bo + l * DM, h1, P1, nullptr, 512, 256, 512);
        k_ln3<<<M / 2, 256, 0, stream>>>(h1, P1, h, ln1s + l * DM, ln1b + l * DM, h1, h1b);
        // FFN1: 128x128 tiles, 512 blocks
        k_mm<1, 1><<<dim3(16, 32, 1), 256, 0, stream>>>(h1b, w1t,
            b1 + l * DI, nullptr, nullptr, midb, 512, 512, 2048);
        if (splitF2) {
            k_mm<0, 0><<<dim3(4, 32, 2), 256, 0, stream>>>(midb, w2t,
                b2 + l * DM, h, P2, nullptr, 2048, 1024, 512);
            k_ln3<<<M / 2, 256, 0, stream>>>(h, P2, h1, ln2s + l * DM, ln2b + l * DM, h, hb);
        } else {
            k_mm<0, 0><<<dim3(4, 32, 1), 256, 0, stream>>>(midb, w2t,
                b2 + l * DM, h, nullptr, nullptr, 2048, 2048, 512);
            k_ln<<<M / 2, 256, 0, stream>>>(h, h1, ln2s + l * DM, ln2b + l * DM, h, hb);
        }
    }

    k_head<<<1, 512, 0, stream>>>(h, Wf, bfp, out);
}

// Round 9
// 1002.452 us; speedup vs baseline: 1.1025x; 1.1025x over previous
//
#include <hip/hip_runtime.h>
#include <math.h>

#define BATCH  4
#define SEQ    1024
#define DM     512
#define DI     2048
#define NH     8
#define DH     64
#define NL     6
#define NOUT   2

typedef unsigned short u16;
typedef short s16x8 __attribute__((ext_vector_type(8)));
typedef float f32x4 __attribute__((ext_vector_type(4)));
typedef unsigned short u16x4 __attribute__((ext_vector_type(4)));

#define MFMA16(a, b, c) __builtin_amdgcn_mfma_f32_16x16x32_bf16((a), (b), (c), 0, 0, 0)

static constexpr float SQRT_D = 22.627416997969522f;

// per-layer bf16 weight slot layout (u16 element offsets)
#define SLOT_WO   786432     // after Wqkvt [1536][512]
#define SLOT_W1   1048576    // after Wot   [512][512]
#define SLOT_W2   2097152    // after W1t   [2048][512]
#define SLOT_E    3145728    // after W2t   [512][2048]
#define SLOT_SZ   3211264    // total u16 per layer (6.125 MB)

__device__ __forceinline__ u16 f2b(float x) {           // f32 -> bf16 (RNE)
    union { float f; unsigned u; } v; v.f = x;
    unsigned r = v.u + 0x7fffu + ((v.u >> 16) & 1u);
    return (u16)(r >> 16);
}
__device__ __forceinline__ float b2f(u16 b) {
    union { unsigned u; float f; } v; v.u = ((unsigned)b) << 16; return v.f;
}

// ---------------------------------------------------------------------------
// Embedding: h = emb[x]*sqrt(D) + pos   (writes f32 h and bf16 hb)
// ---------------------------------------------------------------------------
__global__ __launch_bounds__(256) void k_embed(const int* __restrict__ x,
                                               const float* __restrict__ emb,
                                               const float* __restrict__ pos,
                                               float* __restrict__ h,
                                               u16* __restrict__ hb) {
    const int idx = blockIdx.x * 256 + threadIdx.x;   // float4 index
    const int d4  = idx & 127;
    const int bs  = idx >> 7;
    const int s   = bs & (SEQ - 1);
    const int tok = x[bs];
    const float4 e = ((const float4*)emb)[tok * 128 + d4];
    const float4 p = ((const float4*)pos)[s * 128 + d4];
    float4 r;
    r.x = e.x * SQRT_D + p.x;  r.y = e.y * SQRT_D + p.y;
    r.z = e.z * SQRT_D + p.z;  r.w = e.w * SQRT_D + p.w;
    ((float4*)h)[idx] = r;
    u16x4 rb = { f2b(r.x), f2b(r.y), f2b(r.z), f2b(r.w) };
    ((u16x4*)hb)[idx] = rb;
}

// ---------------------------------------------------------------------------
// Weight convert+transpose to bf16 (1 or 6 layers per dispatch).
// ---------------------------------------------------------------------------
__global__ __launch_bounds__(256) void k_conv(const float* __restrict__ Wq, const float* __restrict__ Wk,
                                              const float* __restrict__ Wv, const float* __restrict__ Wo,
                                              const float* __restrict__ W1, const float* __restrict__ W2,
                                              const float* __restrict__ E,
                                              u16* __restrict__ wbase, int layer0, int slot_stride) {
    const int ll = blockIdx.x / 3136;
    const int tb = blockIdx.x - ll * 3136;
    const int layer = layer0 + ll;
    u16* Wqkvt = wbase + (size_t)ll * slot_stride;
    u16* Wot   = Wqkvt + SLOT_WO;
    u16* W1t   = Wqkvt + SLOT_W1;
    u16* W2t   = Wqkvt + SLOT_W2;
    u16* Ebf   = Wqkvt + SLOT_E;

    if (tb >= 3072) {                                   // E convert (no transpose)
        const int rem = tb - 3072;                      // 0..63
        const int idx = rem * 1024 + threadIdx.x * 4;
        const float4 v = *(const float4*)(E + (size_t)layer * SEQ * DH + idx);
        u16x4 o = { f2b(v.x), f2b(v.y), f2b(v.z), f2b(v.w) };
        *(u16x4*)(Ebf + idx) = o;
        return;
    }
    __shared__ float T[32][33];
    const float* src; u16* dst; int Ksz, Nsz, tk, tn;
    if (tb < 768) {
        const int mat = tb >> 8, rem = tb & 255;
        src = (mat == 0 ? Wq : (mat == 1 ? Wk : Wv)) + (size_t)layer * DM * DM;
        dst = Wqkvt + (size_t)mat * DM * DM;
        Ksz = 512; Nsz = 512; tk = rem & 15; tn = rem >> 4;
    } else if (tb < 1024) {
        const int rem = tb - 768;
        src = Wo + (size_t)layer * DM * DM; dst = Wot;
        Ksz = 512; Nsz = 512; tk = rem & 15; tn = rem >> 4;
    } else if (tb < 2048) {
        const int rem = tb - 1024;
        src = W1 + (size_t)layer * DM * DI; dst = W1t;
        Ksz = 512; Nsz = 2048; tk = rem & 15; tn = rem >> 4;
    } else {
        const int rem = tb - 2048;
        src = W2 + (size_t)layer * DI * DM; dst = W2t;
        Ksz = 2048; Nsz = 512; tk = rem >> 4; tn = rem & 15;
    }
    {
        const int rr = threadIdx.x >> 3, c4 = (threadIdx.x & 7) << 2;
        const float4 v = *(const float4*)(src + (size_t)(tk * 32 + rr) * Nsz + tn * 32 + c4);
        T[rr][c4 + 0] = v.x; T[rr][c4 + 1] = v.y; T[rr][c4 + 2] = v.z; T[rr][c4 + 3] = v.w;
    }
    __syncthreads();
    {
        const int nl = threadIdx.x >> 3, k4 = (threadIdx.x & 7) << 2;
        u16x4 o = { f2b(T[k4 + 0][nl]), f2b(T[k4 + 1][nl]), f2b(T[k4 + 2][nl]), f2b(T[k4 + 3][nl]) };
        *(u16x4*)(dst + (size_t)(tn * 32 + nl) * Ksz + tk * 32 + k4) = o;
    }
}

// ---------------------------------------------------------------------------
// V transpose: vb [B][SEQ][DM] bf16 -> Vt [B][DM][SEQ] bf16. grid (16,32,4).
// ---------------------------------------------------------------------------
__global__ __launch_bounds__(256) void k_vt(const u16* __restrict__ vb,
                                            u16* __restrict__ Vt) {
    __shared__ float T[32][33];
    const int tn = blockIdx.x;       // col tile (DM/32 = 16)
    const int tk = blockIdx.y;       // row tile (SEQ/32 = 32)
    const int b  = blockIdx.z;
    const u16* src = vb + (size_t)b * SEQ * DM;
    u16* dst = Vt + (size_t)b * DM * SEQ;
    {
        const int rr = threadIdx.x >> 3, c4 = (threadIdx.x & 7) << 2;
        const u16x4 v = *(const u16x4*)(src + (size_t)(tk * 32 + rr) * DM + tn * 32 + c4);
        T[rr][c4 + 0] = b2f(v.x); T[rr][c4 + 1] = b2f(v.y);
        T[rr][c4 + 2] = b2f(v.z); T[rr][c4 + 3] = b2f(v.w);
    }
    __syncthreads();
    {
        const int nl = threadIdx.x >> 3, k4 = (threadIdx.x & 7) << 2;
        u16x4 o = { f2b(T[k4 + 0][nl]), f2b(T[k4 + 1][nl]),
                    f2b(T[k4 + 2][nl]), f2b(T[k4 + 3][nl]) };
        *(u16x4*)(dst + (size_t)(tn * 32 + nl) * SEQ + tk * 32 + k4) = o;
    }
}

// ---------------------------------------------------------------------------
// MFMA GEMM, 128x128 tile, BK=32, 4 waves (r7-proven manual staging, pad 40).
// Optional split-K over blockIdx.z (z=0 adds bias->Cf0, z=1 ->Cf1).
// ---------------------------------------------------------------------------
template <int RELU, int WRITE_BF16>
__global__ __launch_bounds__(256) void k_mm(const u16* __restrict__ A,
                                            const u16* __restrict__ Bt,
                                            const float* __restrict__ bias,
                                            float* __restrict__ Cf0,
                                            float* __restrict__ Cf1,
                                            u16* __restrict__ Cb,
                                            int K, int Kslice, int ldc) {
    __shared__ u16 As[128 * 40];
    __shared__ u16 Bs[128 * 40];

    const int n0 = blockIdx.x << 7;
    const int m0 = blockIdx.y << 7;
    const int zz = blockIdx.z;
    const int t  = threadIdx.x;
    const int lane = t & 63, w = t >> 6;
    const int n16 = lane & 15, quad = lane >> 4;
    const int wr = (w & 1) << 6;
    const int wc = (w >> 1) << 6;

    const f32x4 z = {0.f, 0.f, 0.f, 0.f};
    f32x4 acc[4][4];
#pragma unroll
    for (int i = 0; i < 4; ++i)
#pragma unroll
        for (int j = 0; j < 4; ++j) acc[i][j] = z;

    const int sr = t >> 2, sk = (t & 3) << 3;
    const int koff = zz * Kslice;
    const u16* Ag = A  + (size_t)(m0 + sr) * K + koff + sk;
    const u16* Bg = Bt + (size_t)(n0 + sr) * K + koff + sk;

    for (int k0 = 0; k0 < Kslice; k0 += 32) {
        __syncthreads();
        *(uint4*)&As[sr * 40 + sk]        = *(const uint4*)(Ag + k0);
        *(uint4*)&As[(sr + 64) * 40 + sk] = *(const uint4*)(Ag + (size_t)64 * K + k0);
        *(uint4*)&Bs[sr * 40 + sk]        = *(const uint4*)(Bg + k0);
        *(uint4*)&Bs[(sr + 64) * 40 + sk] = *(const uint4*)(Bg + (size_t)64 * K + k0);
        __syncthreads();

        s16x8 af[4], bfr[4];
#pragma unroll
        for (int rb = 0; rb < 4; ++rb)
            af[rb] = *(const s16x8*)&As[(wr + rb * 16 + n16) * 40 + quad * 8];
#pragma unroll
        for (int cb = 0; cb < 4; ++cb)
            bfr[cb] = *(const s16x8*)&Bs[(wc + cb * 16 + n16) * 40 + quad * 8];
#pragma unroll
        for (int rb = 0; rb < 4; ++rb)
#pragma unroll
            for (int cb = 0; cb < 4; ++cb)
                acc[rb][cb] = MFMA16(af[rb], bfr[cb], acc[rb][cb]);
    }

    float* Cf = zz ? Cf1 : Cf0;
#pragma unroll
    for (int cb = 0; cb < 4; ++cb) {
        const int col = n0 + wc + cb * 16 + n16;
        const float bv = (zz == 0) ? bias[col] : 0.f;
#pragma unroll
        for (int rb = 0; rb < 4; ++rb) {
#pragma unroll
            for (int rr = 0; rr < 4; ++rr) {
                const int row = m0 + wr + rb * 16 + quad * 4 + rr;
                float v = acc[rb][cb][rr] + bv;
                if (RELU) v = fmaxf(v, 0.f);
                const size_t idx = (size_t)row * ldc + col;
                if (WRITE_BF16) Cb[idx] = f2b(v);
                else            Cf[idx] = v;
            }
        }
    }
}

// ---------------------------------------------------------------------------
// MFMA GEMM, 64x128 tile, BK=64, 4 waves (r7-proven). bf16 out, QKV-segmented.
// ---------------------------------------------------------------------------
__global__ __launch_bounds__(256) void k_mm64(const u16* __restrict__ A,
                                              const u16* __restrict__ Bt,
                                              const float* __restrict__ bias0,
                                              const float* __restrict__ bias1,
                                              const float* __restrict__ bias2,
                                              u16* __restrict__ Cb,
                                              int K, int ldc, int seg_shift, size_t seg_stride) {
    __shared__ u16 As[64 * 72];
    __shared__ u16 Bs[128 * 72];

    const int n0 = blockIdx.x << 7;
    const int m0 = blockIdx.y << 6;
    const int t  = threadIdx.x;
    const int lane = t & 63, w = t >> 6;
    const int n16 = lane & 15, quad = lane >> 4;
    const int wc = w << 5;
    const int r = t >> 3, o = (t & 7) << 3;

    const f32x4 z = {0.f, 0.f, 0.f, 0.f};
    f32x4 acc[4][2];
#pragma unroll
    for (int i = 0; i < 4; ++i) { acc[i][0] = z; acc[i][1] = z; }

    const u16* Ag = A  + (size_t)(m0 + r) * K + o;
    const u16* Bg = Bt + (size_t)(n0 + r) * K + o;

    for (int k0 = 0; k0 < K; k0 += 64) {
        __syncthreads();
        *(uint4*)&As[r * 72 + o]        = *(const uint4*)(Ag + k0);
        *(uint4*)&As[(r + 32) * 72 + o] = *(const uint4*)(Ag + (size_t)32 * K + k0);
        *(uint4*)&Bs[r * 72 + o]        = *(const uint4*)(Bg + k0);
        *(uint4*)&Bs[(r + 32) * 72 + o] = *(const uint4*)(Bg + (size_t)32 * K + k0);
        *(uint4*)&Bs[(r + 64) * 72 + o] = *(const uint4*)(Bg + (size_t)64 * K + k0);
        *(uint4*)&Bs[(r + 96) * 72 + o] = *(const uint4*)(Bg + (size_t)96 * K + k0);
        __syncthreads();

#pragma unroll
        for (int ks = 0; ks < 2; ++ks) {
            s16x8 af[4], bfr[2];
#pragma unroll
            for (int rb = 0; rb < 4; ++rb)
                af[rb] = *(const s16x8*)&As[(rb * 16 + n16) * 72 + ks * 32 + quad * 8];
#pragma unroll
            for (int cb = 0; cb < 2; ++cb)
                bfr[cb] = *(const s16x8*)&Bs[(wc + cb * 16 + n16) * 72 + ks * 32 + quad * 8];
#pragma unroll
            for (int rb = 0; rb < 4; ++rb)
#pragma unroll
                for (int cb = 0; cb < 2; ++cb)
                    acc[rb][cb] = MFMA16(af[rb], bfr[cb], acc[rb][cb]);
        }
    }

    const int sel = n0 >> seg_shift;
    const int colbase = (n0 & ((1 << seg_shift) - 1)) + wc;
    const float* bias = (sel == 0) ? bias0 : (sel == 1 ? bias1 : bias2);
    const size_t cbase = (size_t)sel * seg_stride;
#pragma unroll
    for (int cb = 0; cb < 2; ++cb) {
        const int col = colbase + cb * 16 + n16;
        const float bv = bias[col];
#pragma unroll
        for (int rb = 0; rb < 4; ++rb)
#pragma unroll
            for (int rr = 0; rr < 4; ++rr) {
                const int row = m0 + rb * 16 + quad * 4 + rr;
                Cb[cbase + (size_t)row * ldc + col] = f2b(acc[rb][cb][rr] + bv);
            }
    }
}

// ---------------------------------------------------------------------------
// MFMA flash relative attention — SINGLE barrier per iter.
// grid (16,8,4), 256 thr = 4 waves. K/V: LDS double-buffered (2 bufs x
// 2-plane [64][32] u16) fed by register prefetch; writes at iter ct target
// buf ct&1, reads at ct-1 used the other -> no consumer barrier. Es 128-row
// ring: write-half at ct == read-half at ct != read-half at ct-1 (only the
// 0->1 transition needs one extra barrier: init read both halves).
// Ps/arena are wave-private rows (in-wave DS ordering, no barriers).
// Srel[ir][ic] = (d<=i0-c0) ? QE[ir][63+d] : 0, d=ic-ir; QE incremental ring
// phys col = (logical + 64*ct) & 127. No online max (logits bounded).
// LDS total 77 KB -> 2 blocks/CU. Barriers: 17 vs r7's 32.
// ---------------------------------------------------------------------------
__global__ __launch_bounds__(256) void k_attn(const u16* __restrict__ Qg,
                                              const u16* __restrict__ Kg,
                                              const u16* __restrict__ Vt,
                                              const u16* __restrict__ Eg,
                                              u16* __restrict__ Og) {
    __shared__ u16 Ks[2 * 4096];      // 2 bufs x 2 planes x [64][32]
    __shared__ u16 Vts[2 * 4096];     // Vts[d][j] = V[c0+j][d]
    __shared__ u16 Ps[64 * 72];
    __shared__ u16 Es[128 * 72];      // E window ring
    __shared__ u16 arena[128 * 72];   // QE bf16, col-major; rows wave-private

    const int i0 = blockIdx.x << 6;
    const int hd = blockIdx.y;
    const int b  = blockIdx.z;
    const int t  = threadIdx.x;
    const int lane = t & 63;
    const int n16 = lane & 15;
    const int quad = lane >> 4;
    const int rw = (t >> 6) << 4;
    const int ir_base = rw + (quad << 2);
    const int a_last = i0 >> 6;
    const int eb0 = 960 - i0;

    const size_t gb  = (size_t)b * SEQ * DM + hd * DH;
    const size_t vtb = ((size_t)b * DM + hd * DH) * SEQ;

    const int r = t >> 3;              // staging row 0..31
    const int o = (t & 7) << 3;        // staging elem offset 0..56
    const int pp = ((o >> 5) << 11) + (o & 31);   // K/V plane offset (u16)

    // Q fragments: iteration-invariant
    const u16* qp = Qg + gb + (size_t)(i0 + rw + n16) * DM + quad * 8;
    const s16x8 qa0 = *(const s16x8*)qp;
    const s16x8 qa1 = *(const s16x8*)(qp + 32);

    // preload ct=0 tiles into registers
    uint4 kr0 = *(const uint4*)(Kg + gb + (size_t)r * DM + o);
    uint4 kr1 = *(const uint4*)(Kg + gb + (size_t)(r + 32) * DM + o);
    uint4 vr0 = *(const uint4*)(Vt + vtb + (size_t)r * SEQ + o);
    uint4 vr1 = *(const uint4*)(Vt + vtb + (size_t)(r + 32) * SEQ + o);
    int e0i = eb0 + r;        e0i = e0i > 1023 ? 1023 : e0i;
    int e1i = eb0 + r + 32;   e1i = e1i > 1023 ? 1023 : e1i;
    int e2i = eb0 + r + 64;   e2i = e2i > 1023 ? 1023 : e2i;
    int e3i = eb0 + r + 96;   e3i = e3i > 1023 ? 1023 : e3i;
    uint4 er0 = *(const uint4*)(Eg + (size_t)e0i * DH + o);
    uint4 er1 = *(const uint4*)(Eg + (size_t)e1i * DH + o);
    uint4 er2 = *(const uint4*)(Eg + (size_t)e2i * DH + o);
    uint4 er3 = *(const uint4*)(Eg + (size_t)e3i * DH + o);

    const f32x4 z = {0.f, 0.f, 0.f, 0.f};
    f32x4 Oa[4] = {z, z, z, z};
    float l_run[4] = {0.f, 0.f, 0.f, 0.f};

    for (int ct = 0; ct < 16; ++ct) {
        const int c0 = ct << 6;
        const bool active = (ct <= a_last);
        const int bsel = (ct & 1) << 12;   // K/V buffer select (4096 u16)

        // only hazard needing an extra barrier: iter-0 read both Es halves,
        // iter-1 writes half 0.
        if (ct == 1 && a_last >= 1) __syncthreads();

        // stage this iter's tiles from prefetched registers
        *(uint4*)&Ks[bsel + pp + r * 32]         = kr0;
        *(uint4*)&Ks[bsel + pp + (r + 32) * 32]  = kr1;
        *(uint4*)&Vts[bsel + pp + r * 32]        = vr0;
        *(uint4*)&Vts[bsel + pp + (r + 32) * 32] = vr1;
        if (ct == 0) {
            *(uint4*)&Es[r * 72 + o]        = er0;
            *(uint4*)&Es[(r + 32) * 72 + o] = er1;
            *(uint4*)&Es[(r + 64) * 72 + o] = er2;
            *(uint4*)&Es[(r + 96) * 72 + o] = er3;
        } else if (active) {
            const int nb = ((ct + 1) & 1) << 6;     // phys base of new half
            *(uint4*)&Es[(nb + r) * 72 + o]      = er0;
            *(uint4*)&Es[(nb + r + 32) * 72 + o] = er1;
        }
        // prefetch ct+1 into registers (overlaps with compute below)
        if (ct < 15) {
            const int cn = c0 + 64;
            kr0 = *(const uint4*)(Kg + gb + (size_t)(cn + r) * DM + o);
            kr1 = *(const uint4*)(Kg + gb + (size_t)(cn + r + 32) * DM + o);
            vr0 = *(const uint4*)(Vt + vtb + (size_t)r * SEQ + cn + o);
            vr1 = *(const uint4*)(Vt + vtb + (size_t)(r + 32) * SEQ + cn + o);
            if (ct + 1 <= a_last) {
                const int ebn = eb0 + 64 * (ct + 1) + 64;   // new-half E rows
                int f0 = ebn + r;      f0 = f0 > 1023 ? 1023 : f0;
                int f1 = ebn + r + 32; f1 = f1 > 1023 ? 1023 : f1;
                er0 = *(const uint4*)(Eg + (size_t)f0 * DH + o);
                er1 = *(const uint4*)(Eg + (size_t)f1 * DH + o);
            }
        }
        __syncthreads();   // the single barrier: tiles visible

        const u16* Kb = Ks + bsel;
        const u16* Vb = Vts + bsel;

        // ---- S = Q K^T
        f32x4 S[4];
#pragma unroll
        for (int cb = 0; cb < 4; ++cb) {
            const s16x8 k0 = *(const s16x8*)&Kb[(cb * 16 + n16) * 32 + quad * 8];
            const s16x8 k1 = *(const s16x8*)&Kb[2048 + (cb * 16 + n16) * 32 + quad * 8];
            S[cb] = MFMA16(qa0, k0, z);
            S[cb] = MFMA16(qa1, k1, S[cb]);
        }

        if (active) {
            if (ct == 0) {       // full QE: logical cols 0..127, phys == logical
#pragma unroll
                for (int ub = 0; ub < 8; ++ub) {
                    const s16x8 e0 = *(const s16x8*)&Es[(ub * 16 + n16) * 72 + quad * 8];
                    const s16x8 e1 = *(const s16x8*)&Es[(ub * 16 + n16) * 72 + quad * 8 + 32];
                    f32x4 qe = MFMA16(qa0, e0, z);
                    qe = MFMA16(qa1, e1, qe);
                    u16x4 pk = { f2b(qe[0]), f2b(qe[1]), f2b(qe[2]), f2b(qe[3]) };
                    *(u16x4*)&arena[(ub * 16 + n16) * 72 + ir_base] = pk;
                }
            } else {             // incremental: new half, logical cols 64..127
                const int pb = ((ct + 1) & 1) << 6;
#pragma unroll
                for (int ub = 0; ub < 4; ++ub) {
                    const s16x8 e0 = *(const s16x8*)&Es[(pb + ub * 16 + n16) * 72 + quad * 8];
                    const s16x8 e1 = *(const s16x8*)&Es[(pb + ub * 16 + n16) * 72 + quad * 8 + 32];
                    f32x4 qe = MFMA16(qa0, e0, z);
                    qe = MFMA16(qa1, e1, qe);
                    u16x4 pk = { f2b(qe[0]), f2b(qe[1]), f2b(qe[2]), f2b(qe[3]) };
                    *(u16x4*)&arena[(pb + ub * 16 + n16) * 72 + ir_base] = pk;
                }
            }
            const int dqc = i0 - c0;
            const int rot = ct << 6;
#pragma unroll
            for (int cb = 0; cb < 4; ++cb)
#pragma unroll
                for (int rr = 0; rr < 4; ++rr) {
                    const int ir = ir_base + rr;
                    const int d = cb * 16 + n16 - ir;
                    const float srel = (d <= dqc)
                        ? b2f(arena[((63 + d + rot) & 127) * 72 + ir]) : 0.f;
                    S[cb][rr] = (S[cb][rr] + srel) * 0.125f;
                }
        } else {
#pragma unroll
            for (int cb = 0; cb < 4; ++cb)
#pragma unroll
                for (int rr = 0; rr < 4; ++rr) S[cb][rr] *= 0.125f;
        }

        // ---- softmax (no max-shift; logits bounded)
        float p[4][4];
#pragma unroll
        for (int cb = 0; cb < 4; ++cb)
#pragma unroll
            for (int rr = 0; rr < 4; ++rr) p[cb][rr] = __expf(S[cb][rr]);
#pragma unroll
        for (int rr = 0; rr < 4; ++rr) {
            float rs = p[0][rr] + p[1][rr] + p[2][rr] + p[3][rr];
            rs += __shfl_xor(rs, 1, 64);
            rs += __shfl_xor(rs, 2, 64);
            rs += __shfl_xor(rs, 4, 64);
            rs += __shfl_xor(rs, 8, 64);
            l_run[rr] += rs;
        }

        // ---- P -> wave-private LDS (A-operand layout), then PV
#pragma unroll
        for (int cb = 0; cb < 4; ++cb)
#pragma unroll
            for (int rr = 0; rr < 4; ++rr)
                Ps[(ir_base + rr) * 72 + cb * 16 + n16] = f2b(p[cb][rr]);

        const s16x8 pa0 = *(const s16x8*)&Ps[(rw + n16) * 72 + quad * 8];
        const s16x8 pa1 = *(const s16x8*)&Ps[(rw + n16) * 72 + quad * 8 + 32];
#pragma unroll
        for (int db = 0; db < 4; ++db) {
            const s16x8 v0 = *(const s16x8*)&Vb[(db * 16 + n16) * 32 + quad * 8];
            const s16x8 v1 = *(const s16x8*)&Vb[2048 + (db * 16 + n16) * 32 + quad * 8];
            Oa[db] = MFMA16(pa0, v0, Oa[db]);
            Oa[db] = MFMA16(pa1, v1, Oa[db]);
        }
    }

#pragma unroll
    for (int rr = 0; rr < 4; ++rr) l_run[rr] = 1.f / l_run[rr];
#pragma unroll
    for (int db = 0; db < 4; ++db)
#pragma unroll
        for (int rr = 0; rr < 4; ++rr) {
            const int row = i0 + ir_base + rr;
            Og[gb + (size_t)row * DM + db * 16 + n16] = f2b(Oa[db][rr] * l_run[rr]);
        }
}

// ---------------------------------------------------------------------------
// LayerNorm(A + R)*sc + bi -> Y (f32, may alias A) and Yb. 2 rows/block.
// ---------------------------------------------------------------------------
__global__ __launch_bounds__(256) void k_ln(const float* __restrict__ A,
                                            const float* __restrict__ R,
                                            const float* __restrict__ sc,
                                            const float* __restrict__ bi,
                                            float* __restrict__ Y,
                                            u16* __restrict__ Yb) {
    const int g = threadIdx.x >> 7;
    const int r = (blockIdx.x << 1) + g;
    const int t = threadIdx.x & 127;
    const int w = threadIdx.x >> 6;
    const float4 a = ((const float4*)(A + (size_t)r * DM))[t];
    const float4 b = ((const float4*)(R + (size_t)r * DM))[t];
    float4 v;
    v.x = a.x + b.x; v.y = a.y + b.y; v.z = a.z + b.z; v.w = a.w + b.w;

    float s = v.x + v.y + v.z + v.w;
#pragma unroll
    for (int o = 32; o > 0; o >>= 1) s += __shfl_down(s, o, 64);
    __shared__ float r1[4], r2[4];
    if ((threadIdx.x & 63) == 0) r1[w] = s;
    __syncthreads();
    const float mean = (r1[g << 1] + r1[(g << 1) + 1]) * (1.f / 512.f);

    float4 d;
    d.x = v.x - mean; d.y = v.y - mean; d.z = v.z - mean; d.w = v.w - mean;
    float q = d.x * d.x + d.y * d.y + d.z * d.z + d.w * d.w;
#pragma unroll
    for (int o = 32; o > 0; o >>= 1) q += __shfl_down(q, o, 64);
    if ((threadIdx.x & 63) == 0) r2[w] = q;
    __syncthreads();
    const float rsq = rsqrtf((r2[g << 1] + r2[(g << 1) + 1]) * (1.f / 512.f) + 1e-6f);

    const float4 s4 = ((const float4*)sc)[t];
    const float4 b4 = ((const float4*)bi)[t];
    float4 y;
    y.x = d.x * rsq * s4.x + b4.x;
    y.y = d.y * rsq * s4.y + b4.y;
    y.z = d.z * rsq * s4.z + b4.z;
    y.w = d.w * rsq * s4.w + b4.w;
    ((float4*)(Y + (size_t)r * DM))[t] = y;
    u16x4 yb = { f2b(y.x), f2b(y.y), f2b(y.z), f2b(y.w) };
    ((u16x4*)(Yb + (size_t)r * DM))[t] = yb;
}

// ---------------------------------------------------------------------------
// LayerNorm(A0 + A1 + R)*sc + bi -> Y, Yb   (split-K partial sum fused in).
// ---------------------------------------------------------------------------
__global__ __launch_bounds__(256) void k_ln3(const float* __restrict__ A0,
                                             const float* __restrict__ A1,
                                             const float* __restrict__ R,
                                             const float* __restrict__ sc,
                                             const float* __restrict__ bi,
                                             float* __restrict__ Y,
                                             u16* __restrict__ Yb) {
    const int g = threadIdx.x >> 7;
    const int r = (blockIdx.x << 1) + g;
    const int t = threadIdx.x & 127;
    const int w = threadIdx.x >> 6;
    const float4 a0 = ((const float4*)(A0 + (size_t)r * DM))[t];
    const float4 a1 = ((const float4*)(A1 + (size_t)r * DM))[t];
    const float4 b  = ((const float4*)(R  + (size_t)r * DM))[t];
    float4 v;
    v.x = a0.x + a1.x + b.x; v.y = a0.y + a1.y + b.y;
    v.z = a0.z + a1.z + b.z; v.w = a0.w + a1.w + b.w;

    float s = v.x + v.y + v.z + v.w;
#pragma unroll
    for (int o = 32; o > 0; o >>= 1) s += __shfl_down(s, o, 64);
    __shared__ float r1[4], r2[4];
    if ((threadIdx.x & 63) == 0) r1[w] = s;
    __syncthreads();
    const float mean = (r1[g << 1] + r1[(g << 1) + 1]) * (1.f / 512.f);

    float4 d;
    d.x = v.x - mean; d.y = v.y - mean; d.z = v.z - mean; d.w = v.w - mean;
    float q = d.x * d.x + d.y * d.y + d.z * d.z + d.w * d.w;
#pragma unroll
    for (int o = 32; o > 0; o >>= 1) q += __shfl_down(q, o, 64);
    if ((threadIdx.x & 63) == 0) r2[w] = q;
    __syncthreads();
    const float rsq = rsqrtf((r2[g << 1] + r2[(g << 1) + 1]) * (1.f / 512.f) + 1e-6f);

    const float4 s4 = ((const float4*)sc)[t];
    const float4 b4 = ((const float4*)bi)[t];
    float4 y;
    y.x = d.x * rsq * s4.x + b4.x;
    y.y = d.y * rsq * s4.y + b4.y;
    y.z = d.z * rsq * s4.z + b4.z;
    y.w = d.w * rsq * s4.w + b4.w;
    ((float4*)(Y + (size_t)r * DM))[t] = y;
    u16x4 yb = { f2b(y.x), f2b(y.y), f2b(y.z), f2b(y.w) };
    ((u16x4*)(Yb + (size_t)r * DM))[t] = yb;
}

// ---------------------------------------------------------------------------
// out[b,o] = tanh(h[b,0,:] @ Wf[:,o] + bf[o])
// ---------------------------------------------------------------------------
__global__ __launch_bounds__(512) void k_head(const float* __restrict__ h,
                                              const float* __restrict__ Wf,
                                              const float* __restrict__ bf,
                                              float* __restrict__ out) {
    const int t = threadIdx.x;
    const int w = t >> 6, lane = t & 63;
    const int b = w >> 1, oo = w & 1;
    float s = 0.f;
    for (int d = lane; d < DM; d += 64)
        s += h[(size_t)b * SEQ * DM + d] * Wf[d * NOUT + oo];
#pragma unroll
    for (int o = 32; o > 0; o >>= 1) s += __shfl_down(s, o, 64);
    if (lane == 0) out[b * NOUT + oo] = tanhf(s + bf[oo]);
}

// ---------------------------------------------------------------------------
extern "C" void kernel_launch(void* const* d_in, const int* in_sizes, int n_in,
                              void* d_out, int out_size, void* d_ws, size_t ws_size,
                              hipStream_t stream) {
    const int*   x    = (const int*)d_in[0];
    const float* emb  = (const float*)d_in[1];
    const float* pos  = (const float*)d_in[2];
    const float* Wq   = (const float*)d_in[3];
    const float* bq   = (const float*)d_in[4];
    const float* Wk   = (const float*)d_in[5];
    const float* bk   = (const float*)d_in[6];
    const float* Wv   = (const float*)d_in[7];
    const float* bv   = (const float*)d_in[8];
    const float* Wo   = (const float*)d_in[9];
    const float* bo   = (const float*)d_in[10];
    const float* E    = (const float*)d_in[11];
    const float* W1   = (const float*)d_in[12];
    const float* b1   = (const float*)d_in[13];
    const float* W2   = (const float*)d_in[14];
    const float* b2   = (const float*)d_in[15];
    const float* ln1s = (const float*)d_in[16];
    const float* ln1b = (const float*)d_in[17];
    const float* ln2s = (const float*)d_in[18];
    const float* ln2b = (const float*)d_in[19];
    const float* Wf   = (const float*)d_in[20];
    const float* bfp  = (const float*)d_in[21];
    float* out = (float*)d_out;

    // Workspace map (no trailing backslash in these comments!)
    char* W = (char*)d_ws;
    float* h    = (float*)(W);                   // 8 MB f32 residual
    float* h1   = (float*)(W + (8u  << 20));     // 8 MB f32
    u16*   hb   = (u16*)  (W + (16u << 20));     // 4 MB bf16 of h
    u16*   h1b  = (u16*)  (W + (20u << 20));     // 4 MB bf16 of h1 (FFN phase)
    u16*   Vt   = h1b;                           // Vt [B][DM][SEQ] aliases h1b (attn phase)
    u16*   qb   = (u16*)  (W + (24u << 20));     // 4 MB q
    u16*   kb   = (u16*)  (W + (28u << 20));     // 4 MB k
    u16*   vb   = (u16*)  (W + (32u << 20));     // 4 MB v (row-major)
    u16*   tb   = (u16*)  (W + (36u << 20));     // 4 MB attention out
    u16*   midb = qb;                            // FFN inner [4096][2048], aliases 24..40 MB
    float* P1   = (float*)(W + (24u << 20));     // Wo split partial, aliases qb+kb (dead then)
    u16*   Wb   = (u16*)  (W + (40u << 20));     // weight slots (1 or 6 x 6.125 MB)

    // all-layer weight conversion if workspace allows (40 + 6*6.125 = 76.75 MB)
    const bool all = ws_size >= (size_t)80478208ull;
    // FFN2 split partial region right after the weight slots, if room
    const size_t off_p2 = (40ull << 20) + (size_t)(all ? 6 : 1) * SLOT_SZ * 2;
    const bool splitF2 = ws_size >= off_p2 + (8ull << 20);
    float* P2 = (float*)(W + off_p2);

    const int M = BATCH * SEQ;                   // 4096
    const size_t SEG = (size_t)M * DM;           // q->k->v segment stride (elems)

    k_embed<<<(BATCH * SEQ * DM / 4) / 256, 256, 0, stream>>>(x, emb, pos, h, hb);
    if (all)
        k_conv<<<6 * 3136, 256, 0, stream>>>(Wq, Wk, Wv, Wo, W1, W2, E, Wb, 0, SLOT_SZ);

    for (int l = 0; l < NL; ++l) {
        if (!all)
            k_conv<<<3136, 256, 0, stream>>>(Wq, Wk, Wv, Wo, W1, W2, E, Wb, l, 0);
        u16* wl   = Wb + (size_t)(all ? l : 0) * SLOT_SZ;
        u16* wqkv = wl;
        u16* wot  = wl + SLOT_WO;
        u16* w1t  = wl + SLOT_W1;
        u16* w2t  = wl + SLOT_W2;
        u16* ebf  = wl + SLOT_E;

        // QKV: 64x128 tiles, 768 blocks (3/CU)
        k_mm64<<<dim3(12, 64), 256, 0, stream>>>(hb, wqkv,
            bq + l * DM, bk + l * DM, bv + l * DM, qb, 512, 512, 9, SEG);
        k_vt<<<dim3(16, 32, 4), 256, 0, stream>>>(vb, Vt);
        k_attn<<<dim3(16, 8, 4), 256, 0, stream>>>(qb, kb, Vt, ebf, tb);
        // Wo: split-K=2 (256 blocks), partials summed inside k_ln3
        k_mm<0, 0><<<dim3(4, 32, 2), 256, 0, stream>>>(tb, wot,
            bo + l * DM, h1, P1, nullptr, 512, 256, 512);
        k_ln3<<<M / 2, 256, 0, stream>>>(h1, P1, h, ln1s + l * DM, ln1b + l * DM, h1, h1b);
        // FFN1: 128x128 tiles, 512 blocks
        k_mm<1, 1><<<dim3(16, 32, 1), 256, 0, stream>>>(h1b, w1t,
            b1 + l * DI, nullptr, nullptr, midb, 512, 512, 2048);
        if (splitF2) {
            k_mm<0, 0><<<dim3(4, 32, 2), 256, 0, stream>>>(midb, w2t,
                b2 + l * DM, h, P2, nullptr, 2048, 1024, 512);
            k_ln3<<<M / 2, 256, 0, stream>>>(h, P2, h1, ln2s + l * DM, ln2b + l * DM, h, hb);
        } else {
            k_mm<0, 0><<<dim3(4, 32, 1), 256, 0, stream>>>(midb, w2t,
                b2 + l * DM, h, nullptr, nullptr, 2048, 2048, 512);
            k_ln<<<M / 2, 256, 0, stream>>>(h, h1, ln2s + l * DM, ln2b + l * DM, h, hb);
        }
    }

    k_head<<<1, 512, 0, stream>>>(h, Wf, bfp, out);
}